// Round 10
// baseline (249.159 us; speedup 1.0000x reference)
//
#include <hip/hip_runtime.h>
#include <hip/hip_bf16.h>
#include <hip/hip_fp16.h>

#define NN 50000
#define EE 800000
constexpr float BN_EPS = 1e-5f;

typedef float  f32x4  __attribute__((ext_vector_type(4)));
typedef short  s16x8  __attribute__((ext_vector_type(8)));
typedef __bf16 bf16x8 __attribute__((ext_vector_type(8)));

struct __align__(8) Edge { int s; float w; };

// fp32 -> bf16 hi/lo split (RNE both times); hi+lo carries ~16 mantissa bits
__device__ inline void split2(float f, short& h, short& l) {
    unsigned u  = __builtin_bit_cast(unsigned, f);
    unsigned hr = (u + 0x7fffu + ((u >> 16) & 1u)) >> 16;
    h = (short)hr;
    float hf = __builtin_bit_cast(float, hr << 16);
    float r  = f - hf;
    unsigned u2 = __builtin_bit_cast(unsigned, r);
    unsigned lr = (u2 + 0x7fffu + ((u2 >> 16) & 1u)) >> 16;
    l = (short)lr;
}
__device__ inline f32x4 mfma_bf16(s16x8 a, s16x8 b, f32x4 c) {
    return __builtin_amdgcn_mfma_f32_16x16x32_bf16(
        __builtin_bit_cast(bf16x8, a), __builtin_bit_cast(bf16x8, b), c, 0, 0, 0);
}

// ---------------- small utility kernels ----------------
__global__ __launch_bounds__(256) void k_zero_int(int* p, int n) {
    int i = blockIdx.x * 256 + threadIdx.x;
    if (i < n) p[i] = 0;
}

// ---------------- CSR build: 1 atomic/edge total ----------------
__global__ __launch_bounds__(256) void k_hist_rank(const int* __restrict__ dst,
                                                   int* __restrict__ cnt,
                                                   int* __restrict__ rank) {
    int e = blockIdx.x * 256 + threadIdx.x;
    if (e < EE) rank[e] = atomicAdd(&cnt[dst[e]], 1);
}
__global__ __launch_bounds__(256) void k_scan1(const int* __restrict__ cnt,
                                               int* __restrict__ excl,
                                               int* __restrict__ blksum) {
    __shared__ int sh[256];
    int tid = threadIdx.x;
    int i = blockIdx.x * 256 + tid;
    int v = (i < NN) ? cnt[i] : 0;
    sh[tid] = v;
    __syncthreads();
    #pragma unroll
    for (int off = 1; off < 256; off <<= 1) {
        int x = (tid >= off) ? sh[tid - off] : 0;
        __syncthreads();
        sh[tid] += x;
        __syncthreads();
    }
    if (i < NN) excl[i] = sh[tid] - v;
    if (tid == 255) blksum[blockIdx.x] = sh[255];
}
__global__ __launch_bounds__(256) void k_scan2(int* blksum, int nblk) {
    __shared__ int sh[256];
    int tid = threadIdx.x;
    sh[tid] = (tid < nblk) ? blksum[tid] : 0;
    __syncthreads();
    #pragma unroll
    for (int off = 1; off < 256; off <<= 1) {
        int x = (tid >= off) ? sh[tid - off] : 0;
        __syncthreads();
        sh[tid] += x;
        __syncthreads();
    }
    if (tid < nblk) blksum[tid] = sh[tid];
}
__global__ __launch_bounds__(256) void k_scan3(const int* __restrict__ excl,
                                               const int* __restrict__ blksum,
                                               int* __restrict__ rowptr) {
    int i = blockIdx.x * 256 + threadIdx.x;
    if (i < NN)
        rowptr[i] = excl[i] + (blockIdx.x > 0 ? blksum[blockIdx.x - 1] : 0);
    if (i == 0) rowptr[NN] = EE;
}
__global__ __launch_bounds__(256) void k_place2(const int* __restrict__ src,
                                                const int* __restrict__ dst,
                                                const float* __restrict__ w,
                                                const int* __restrict__ rowptr,
                                                const int* __restrict__ rank,
                                                Edge* __restrict__ csr_e) {
    int e = blockIdx.x * 256 + threadIdx.x;
    if (e >= EE) return;
    int slot = rowptr[dst[e]] + rank[e];
    Edge ed; ed.s = src[e]; ed.w = w[e];
    csr_e[slot] = ed;
}
__global__ __launch_bounds__(256) void k_deg_dinv(const int* __restrict__ rowptr,
                                                  const Edge* __restrict__ csr_e,
                                                  float* __restrict__ dinv) {
    int i = blockIdx.x * 256 + threadIdx.x;
    if (i >= NN) return;
    int e0 = rowptr[i], e1 = rowptr[i + 1];
    float s = 1.0f;
    for (int e = e0; e < e1; e++) s += csr_e[e].w;
    dinv[i] = rsqrtf(s);
}
// fold dinv[src] into edge weight: ed.w = w * dinv[s]
__global__ __launch_bounds__(256) void k_edge_coef(Edge* __restrict__ csr_e,
                                                   const float* __restrict__ dinv) {
    int e = blockIdx.x * 256 + threadIdx.x;
    if (e < EE) {
        Edge ed = csr_e[e];
        ed.w *= dinv[ed.s];
        csr_e[e] = ed;
    }
}

// ---------------- all weights: transpose + bf16 hi/lo split (one kernel) ----------------
__device__ inline void cvt_one(const float* W, short* Th, short* Tl, int idx, int K) {
    int k = idx >> 7, c = idx & 127;
    short h, l;
    split2(W[idx], h, l);
    Th[c * K + k] = h;
    Tl[c * K + k] = l;
}
__global__ __launch_bounds__(256) void k_cvt_all(const float* __restrict__ W1,
                                                 const float* __restrict__ W2,
                                                 const float* __restrict__ Wf1,
                                                 short* W1th, short* W1tl,
                                                 short* W2th, short* W2tl,
                                                 short* Wfth, short* Wftl) {
    int idx = blockIdx.x * 256 + threadIdx.x;
    if (idx < 16384)       cvt_one(W1,  W1th, W1tl, idx, 128);
    else if (idx < 32768)  cvt_one(W2,  W2th, W2tl, idx - 16384, 128);
    else if (idx < 81920)  cvt_one(Wf1, Wfth, Wftl, idx - 32768, 384);
}

// ---------------- staging helper: load 8 elems (fp32 or fp16), BN fold, split ----------------
__device__ inline void stage_a(const void* X, bool xfp16, const float* sc, const float* sh,
                               int gr, int n, int kbase, int seg, short* h, short* l) {
    float f[8];
    if (gr < n) {
        if (xfp16) {
            const __half* Xh = (const __half*)X;
            s16x8 raw = *(const s16x8*)&Xh[(size_t)gr * 128 + kbase + seg * 8];
            union { s16x8 r; __half2 h2[4]; } u; u.r = raw;
            #pragma unroll
            for (int i = 0; i < 4; i++) {
                float2 f2 = __half22float2(u.h2[i]);
                f[2 * i] = f2.x; f[2 * i + 1] = f2.y;
            }
        } else {
            const float* Xf = (const float*)X;
            float4 v0 = *(const float4*)&Xf[(size_t)gr * 128 + kbase + seg * 8];
            float4 v1 = *(const float4*)&Xf[(size_t)gr * 128 + kbase + seg * 8 + 4];
            f[0]=v0.x; f[1]=v0.y; f[2]=v0.z; f[3]=v0.w;
            f[4]=v1.x; f[5]=v1.y; f[6]=v1.z; f[7]=v1.w;
        }
    } else {
        #pragma unroll
        for (int i = 0; i < 8; i++) f[i] = 0.f;
    }
    if (sc) {
        float scv[8], shv[8];
        *(float4*)&scv[0] = *(const float4*)&sc[kbase + seg * 8];
        *(float4*)&scv[4] = *(const float4*)&sc[kbase + seg * 8 + 4];
        *(float4*)&shv[0] = *(const float4*)&sh[kbase + seg * 8];
        *(float4*)&shv[4] = *(const float4*)&sh[kbase + seg * 8 + 4];
        #pragma unroll
        for (int i = 0; i < 8; i++) f[i] = fmaf(f[i], scv[i], shv[i]);
    }
    #pragma unroll
    for (int i = 0; i < 8; i++) split2(f[i], h[i], l[i]);
}

// ---------------- MFMA split-bf16 GEMM (fp32 or fp16 input, BN fold), fp16 output ----------------
__global__ __launch_bounds__(256) void gemm_mfma(const void* __restrict__ X, int xfp16,
                                                 const float* __restrict__ sc,
                                                 const float* __restrict__ sh,
                                                 const short* __restrict__ WTh,
                                                 const short* __restrict__ WTl,
                                                 __half* __restrict__ Y, int n) {
    __shared__ __align__(16) short As[2][64][40];
    __shared__ __align__(16) short Bs[2][128][40];
    int tid  = threadIdx.x;
    int row0 = blockIdx.x * 64;
    int w = tid >> 6, lane = tid & 63;
    int wr = w >> 1, wc = w & 1;
    int fr = lane & 15, fq = lane >> 4;
    f32x4 acc[2][4] = {};
    for (int k0 = 0; k0 < 128; k0 += 32) {
        {
            int r = tid >> 2, seg = tid & 3;
            short h[8], l[8];
            stage_a(X, xfp16 != 0, sc, sh, row0 + r, n, k0, seg, h, l);
            *(s16x8*)&As[0][r][seg * 8] = *(s16x8*)h;
            *(s16x8*)&As[1][r][seg * 8] = *(s16x8*)l;
        }
        #pragma unroll
        for (int rd = 0; rd < 2; rd++) {
            int idx = rd * 256 + tid;
            int c = idx >> 2, seg = idx & 3;
            *(s16x8*)&Bs[0][c][seg * 8] = *(const s16x8*)&WTh[c * 128 + k0 + seg * 8];
            *(s16x8*)&Bs[1][c][seg * 8] = *(const s16x8*)&WTl[c * 128 + k0 + seg * 8];
        }
        __syncthreads();
        s16x8 ah[2], al[2], bh[4], bl[4];
        #pragma unroll
        for (int m = 0; m < 2; m++) {
            int r = wr * 32 + m * 16 + fr;
            ah[m] = *(s16x8*)&As[0][r][fq * 8];
            al[m] = *(s16x8*)&As[1][r][fq * 8];
        }
        #pragma unroll
        for (int nf = 0; nf < 4; nf++) {
            int c = wc * 64 + nf * 16 + fr;
            bh[nf] = *(s16x8*)&Bs[0][c][fq * 8];
            bl[nf] = *(s16x8*)&Bs[1][c][fq * 8];
        }
        #pragma unroll
        for (int m = 0; m < 2; m++)
            #pragma unroll
            for (int nf = 0; nf < 4; nf++) {
                acc[m][nf] = mfma_bf16(ah[m], bh[nf], acc[m][nf]);
                acc[m][nf] = mfma_bf16(ah[m], bl[nf], acc[m][nf]);
                acc[m][nf] = mfma_bf16(al[m], bh[nf], acc[m][nf]);
            }
        __syncthreads();
    }
    #pragma unroll
    for (int m = 0; m < 2; m++)
        #pragma unroll
        for (int nf = 0; nf < 4; nf++)
            #pragma unroll
            for (int j = 0; j < 4; j++) {
                int gr = row0 + wr * 32 + m * 16 + fq * 4 + j;
                int gc = wc * 64 + nf * 16 + fr;
                if (gr < n) Y[(size_t)gr * 128 + gc] = __float2half(acc[m][nf][j]);
            }
}

// ---------------- MFMA head: [x fp32 | h1 fp16+BN | h2 fp16+BN] @ Wf1 + fused tail ----------------
__global__ __launch_bounds__(256) void gemm_head_mfma(const float* __restrict__ X0,
                                                      const __half* __restrict__ X1,
                                                      const __half* __restrict__ X2,
                                                      const float* __restrict__ sc1,
                                                      const float* __restrict__ sh1,
                                                      const float* __restrict__ sc2,
                                                      const float* __restrict__ sh2,
                                                      const short* __restrict__ WTh,
                                                      const short* __restrict__ WTl,
                                                      const float* __restrict__ bf1,
                                                      const float* __restrict__ Wf2,
                                                      const float* __restrict__ bf2,
                                                      float* __restrict__ out) {
    __shared__ __align__(16) short As[2][64][40];
    __shared__ __align__(16) short Bs[2][128][40];
    __shared__ float red[64];
    int tid  = threadIdx.x;
    int row0 = blockIdx.x * 64;
    int w = tid >> 6, lane = tid & 63;
    int wr = w >> 1, wc = w & 1;
    int fr = lane & 15, fq = lane >> 4;
    f32x4 acc[2][4] = {};
    for (int k0 = 0; k0 < 384; k0 += 32) {
        const void*  S     = (k0 < 128) ? (const void*)X0 : (k0 < 256) ? (const void*)X1 : (const void*)X2;
        bool         sfp16 = (k0 >= 128);
        const float* scp   = (k0 < 128) ? nullptr : (k0 < 256) ? sc1 : sc2;
        const float* shp   = (k0 < 128) ? nullptr : (k0 < 256) ? sh1 : sh2;
        int kb = k0 & 127;
        {
            int r = tid >> 2, seg = tid & 3;
            short h[8], l[8];
            stage_a(S, sfp16, scp, shp, row0 + r, NN, kb, seg, h, l);
            *(s16x8*)&As[0][r][seg * 8] = *(s16x8*)h;
            *(s16x8*)&As[1][r][seg * 8] = *(s16x8*)l;
        }
        #pragma unroll
        for (int rd = 0; rd < 2; rd++) {
            int idx = rd * 256 + tid;
            int c = idx >> 2, seg = idx & 3;
            *(s16x8*)&Bs[0][c][seg * 8] = *(const s16x8*)&WTh[c * 384 + k0 + seg * 8];
            *(s16x8*)&Bs[1][c][seg * 8] = *(const s16x8*)&WTl[c * 384 + k0 + seg * 8];
        }
        __syncthreads();
        s16x8 ah[2], al[2], bh[4], bl[4];
        #pragma unroll
        for (int m = 0; m < 2; m++) {
            int r = wr * 32 + m * 16 + fr;
            ah[m] = *(s16x8*)&As[0][r][fq * 8];
            al[m] = *(s16x8*)&As[1][r][fq * 8];
        }
        #pragma unroll
        for (int nf = 0; nf < 4; nf++) {
            int c = wc * 64 + nf * 16 + fr;
            bh[nf] = *(s16x8*)&Bs[0][c][fq * 8];
            bl[nf] = *(s16x8*)&Bs[1][c][fq * 8];
        }
        #pragma unroll
        for (int m = 0; m < 2; m++)
            #pragma unroll
            for (int nf = 0; nf < 4; nf++) {
                acc[m][nf] = mfma_bf16(ah[m], bh[nf], acc[m][nf]);
                acc[m][nf] = mfma_bf16(ah[m], bl[nf], acc[m][nf]);
                acc[m][nf] = mfma_bf16(al[m], bh[nf], acc[m][nf]);
            }
        __syncthreads();
    }
    if (tid < 64) red[tid] = 0.f;
    __syncthreads();
    float ps[2][4] = {};
    #pragma unroll
    for (int m = 0; m < 2; m++)
        #pragma unroll
        for (int nf = 0; nf < 4; nf++) {
            int gc = wc * 64 + nf * 16 + fr;
            float b1v = bf1[gc];
            float w2v = Wf2[gc];
            #pragma unroll
            for (int j = 0; j < 4; j++) {
                float u = fmaxf(acc[m][nf][j] + b1v, 0.f);
                ps[m][j] = fmaf(u, w2v, ps[m][j]);
            }
        }
    #pragma unroll
    for (int off = 1; off <= 8; off <<= 1)
        #pragma unroll
        for (int m = 0; m < 2; m++)
            #pragma unroll
            for (int j = 0; j < 4; j++)
                ps[m][j] += __shfl_xor(ps[m][j], off, 64);
    if (fr == 0) {
        #pragma unroll
        for (int m = 0; m < 2; m++)
            #pragma unroll
            for (int j = 0; j < 4; j++)
                atomicAdd(&red[wr * 32 + m * 16 + fq * 4 + j], ps[m][j]);
    }
    __syncthreads();
    if (tid < 64 && row0 + tid < NN)
        out[row0 + tid] = fmaxf(red[tid] + bf2[0], 0.f);
}

// ---------------- aggregate (CSR): 512 thr, 8 waves x 4 nodes; 4 edges x 16 lanes x 16B ----------------
// h[d] = relu( (t[d]*dinv_d + sum_e coef_e*t[s_e]) * dinv_d + b ); h stored fp16
__global__ __launch_bounds__(512) void k_agg_stats(const __half* __restrict__ t,
                                                   const float* __restrict__ dinv,
                                                   const float* __restrict__ b,
                                                   const int* __restrict__ rowptr,
                                                   const Edge* __restrict__ csr_e,
                                                   __half* __restrict__ h,
                                                   float* __restrict__ partS,
                                                   float* __restrict__ partSS) {
    int wv   = threadIdx.x >> 6;   // wave 0..7
    int lane = threadIdx.x & 63;
    int sub  = lane >> 4;          // edge slot 0..3
    int sl   = lane & 15;          // col group: 8 cols each
    float bb[8];
    *(float4*)&bb[0] = *(const float4*)&b[sl * 8];
    *(float4*)&bb[4] = *(const float4*)&b[sl * 8 + 4];
    float sS[8] = {}, sSS[8] = {};
    #pragma unroll 1
    for (int ni = 0; ni < 4; ni++) {
        int wid = blockIdx.x * 32 + wv * 4 + ni;
        if (wid >= NN) break;
        float di = dinv[wid];
        float acc[8];
        if (sub == 0) {              // self-loop term
            s16x8 raw = *(const s16x8*)&t[(size_t)wid * 128 + sl * 8];
            union { s16x8 r; __half2 h2[4]; } u; u.r = raw;
            #pragma unroll
            for (int i = 0; i < 4; i++) {
                float2 f = __half22float2(u.h2[i]);
                acc[2 * i]     = f.x * di;
                acc[2 * i + 1] = f.y * di;
            }
        } else {
            #pragma unroll
            for (int i = 0; i < 8; i++) acc[i] = 0.f;
        }
        int e0 = rowptr[wid], e1 = rowptr[wid + 1];
        #pragma unroll 4
        for (int e = e0; e < e1; e += 4) {
            int ee   = e + sub;
            bool v   = ee < e1;
            Edge ed  = csr_e[v ? ee : e0];                  // 8B load (e0 valid: loop ran)
            float cw = v ? ed.w : 0.f;
            s16x8 raw = *(const s16x8*)&t[(size_t)ed.s * 128 + sl * 8];  // 16B gather
            union { s16x8 r; __half2 h2[4]; } u; u.r = raw;
            #pragma unroll
            for (int i = 0; i < 4; i++) {
                float2 f = __half22float2(u.h2[i]);
                acc[2 * i]     = fmaf(f.x, cw, acc[2 * i]);
                acc[2 * i + 1] = fmaf(f.y, cw, acc[2 * i + 1]);
            }
        }
        // reduce 4 edge slots
        #pragma unroll
        for (int i = 0; i < 8; i++) {
            acc[i] += __shfl_xor(acc[i], 16, 64);
            acc[i] += __shfl_xor(acc[i], 32, 64);
        }
        if (sub == 0) {
            float hv[8];
            union { s16x8 r; __half2 h2[4]; } o;
            #pragma unroll
            for (int i = 0; i < 8; i++) {
                hv[i] = fmaxf(fmaf(acc[i], di, bb[i]), 0.f);
                sS[i]  += hv[i];
                sSS[i] += hv[i] * hv[i];
            }
            #pragma unroll
            for (int i = 0; i < 4; i++)
                o.h2[i] = __floats2half2_rn(hv[2 * i], hv[2 * i + 1]);
            *(s16x8*)&h[(size_t)wid * 128 + sl * 8] = o.r;
        }
    }
    __shared__ float s_s[8][128], s_ss[8][128];
    if (sub == 0) {
        #pragma unroll
        for (int i = 0; i < 8; i++) {
            s_s [wv][sl * 8 + i] = sS[i];
            s_ss[wv][sl * 8 + i] = sSS[i];
        }
    }
    __syncthreads();
    if (threadIdx.x < 128) {
        int c = threadIdx.x;
        float S = 0.f, SS = 0.f;
        #pragma unroll
        for (int k = 0; k < 8; k++) { S += s_s[k][c]; SS += s_ss[k][c]; }
        partS [blockIdx.x * 128 + c] = S;
        partSS[blockIdx.x * 128 + c] = SS;
    }
}

// ---------------- parallel reduce partials -> BN scale/shift ----------------
__global__ __launch_bounds__(256) void k_stats(const float* __restrict__ partS,
                                               const float* __restrict__ partSS,
                                               int nblk,
                                               const float* __restrict__ g,
                                               const float* __restrict__ be,
                                               float* __restrict__ scale,
                                               float* __restrict__ shift) {
    int c   = blockIdx.x;
    int tid = threadIdx.x;
    float s = 0.f, ss = 0.f;
    for (int b = tid; b < nblk; b += 256) {
        s  += partS [b * 128 + c];
        ss += partSS[b * 128 + c];
    }
    #pragma unroll
    for (int off = 32; off > 0; off >>= 1) {
        s  += __shfl_down(s,  off, 64);
        ss += __shfl_down(ss, off, 64);
    }
    __shared__ float sh_s[4], sh_ss[4];
    int wv = tid >> 6, lane = tid & 63;
    if (lane == 0) { sh_s[wv] = s; sh_ss[wv] = ss; }
    __syncthreads();
    if (tid == 0) {
        float S  = sh_s[0]  + sh_s[1]  + sh_s[2]  + sh_s[3];
        float SS = sh_ss[0] + sh_ss[1] + sh_ss[2] + sh_ss[3];
        float mean = S / (float)NN;
        float var  = SS / (float)NN - mean * mean;
        float sc   = g[c] * rsqrtf(var + BN_EPS);
        scale[c] = sc;
        shift[c] = be[c] - mean * sc;
    }
}

// ---------------- launch ----------------
extern "C" void kernel_launch(void* const* d_in, const int* in_sizes, int n_in,
                              void* d_out, int out_size, void* d_ws, size_t ws_size,
                              hipStream_t stream) {
    const float* x   = (const float*)d_in[0];
    const int*   ei  = (const int*)d_in[1];
    const float* ew  = (const float*)d_in[2];
    const float* W1  = (const float*)d_in[3];
    const float* b1  = (const float*)d_in[4];
    const float* W2  = (const float*)d_in[5];
    const float* b2  = (const float*)d_in[6];
    const float* g1  = (const float*)d_in[7];
    const float* be1 = (const float*)d_in[8];
    const float* g2  = (const float*)d_in[9];
    const float* be2 = (const float*)d_in[10];
    const float* Wf1 = (const float*)d_in[11];
    const float* bf1 = (const float*)d_in[12];
    const float* Wf2 = (const float*)d_in[13];
    const float* bf2 = (const float*)d_in[14];
    float* out = (float*)d_out;

    const int* src = ei;
    const int* dst = ei + EE;

    const int NAGG = (NN + 31) / 32;  // 1563 blocks (32 nodes each, 8 waves x 4)

    // workspace carve
    float* w = (float*)d_ws;
    __half* t      = (__half*)w;  w += (size_t)NN * 64;    // NN*128 halves
    __half* h1     = (__half*)w;  w += (size_t)NN * 64;
    __half* h2     = (__half*)w;  w += (size_t)NN * 64;
    float* dinv    = w;  w += 50048;
    float* partS   = w;  w += (size_t)NAGG * 128;
    float* partSS  = w;  w += (size_t)NAGG * 128;
    float* scale1  = w;  w += 128;
    float* shift1  = w;  w += 128;
    float* scale2  = w;  w += 128;
    float* shift2  = w;  w += 128;
    Edge* csr_e    = (Edge*)w;  w += 2 * (size_t)EE;       // 8B per edge
    int* iw        = (int*)w;
    int* rowptr    = iw; iw += 50056;
    int* cnt       = iw; iw += 50048;
    int* excl      = iw; iw += 50048;
    int* blksum    = iw; iw += 256;
    short* sw      = (short*)iw;
    short* W1th = sw; sw += 128 * 128;
    short* W1tl = sw; sw += 128 * 128;
    short* W2th = sw; sw += 128 * 128;
    short* W2tl = sw; sw += 128 * 128;
    short* Wfth = sw; sw += 128 * 384;
    short* Wftl = sw; sw += 128 * 384;
    // rank aliases t region: CSR build completes before gemm writes t (same stream)
    int* rank = (int*)t;

    const int GN = (NN + 255) / 256;
    const int GE = (EE + 255) / 256;
    const int NBLK = (NN + 63) / 64;  // 782

    // weights (one kernel) + CSR build
    k_cvt_all<<<(81920 + 255) / 256, 256, 0, stream>>>(W1, W2, Wf1, W1th, W1tl,
                                                       W2th, W2tl, Wfth, Wftl);
    k_zero_int<<<GN, 256, 0, stream>>>(cnt, 50048);
    k_hist_rank<<<GE, 256, 0, stream>>>(dst, cnt, rank);
    k_scan1<<<GN, 256, 0, stream>>>(cnt, excl, blksum);
    k_scan2<<<1, 256, 0, stream>>>(blksum, GN);
    k_scan3<<<GN, 256, 0, stream>>>(excl, blksum, rowptr);
    k_place2<<<GE, 256, 0, stream>>>(src, dst, ew, rowptr, rank, csr_e);
    k_deg_dinv<<<GN, 256, 0, stream>>>(rowptr, csr_e, dinv);
    k_edge_coef<<<GE, 256, 0, stream>>>(csr_e, dinv);

    // layer 1
    gemm_mfma<<<NBLK, 256, 0, stream>>>(x, 0, nullptr, nullptr, W1th, W1tl, t, NN);
    k_agg_stats<<<NAGG, 512, 0, stream>>>(t, dinv, b1, rowptr, csr_e, h1, partS, partSS);
    k_stats<<<128, 256, 0, stream>>>(partS, partSS, NAGG, g1, be1, scale1, shift1);

    // layer 2 (BN1 folded into staging, fp16 input)
    gemm_mfma<<<NBLK, 256, 0, stream>>>(h1, 1, scale1, shift1, W2th, W2tl, t, NN);
    k_agg_stats<<<NAGG, 512, 0, stream>>>(t, dinv, b2, rowptr, csr_e, h2, partS, partSS);
    k_stats<<<128, 256, 0, stream>>>(partS, partSS, NAGG, g2, be2, scale2, shift2);

    // head (BN1/BN2 folded into staging of X1/X2)
    gemm_head_mfma<<<NBLK, 256, 0, stream>>>(x, h1, h2, scale1, shift1, scale2, shift2,
                                             Wfth, Wftl, bf1, Wf2, bf2, out);
}

// Round 11
// 223.691 us; speedup vs baseline: 1.1139x; 1.1139x over previous
//
#include <hip/hip_runtime.h>
#include <hip/hip_bf16.h>
#include <hip/hip_fp16.h>

#define NN 50000
#define EE 800000
#define NPAD 50048
constexpr float BN_EPS = 1e-5f;

typedef float  f32x4  __attribute__((ext_vector_type(4)));
typedef short  s16x8  __attribute__((ext_vector_type(8)));
typedef __bf16 bf16x8 __attribute__((ext_vector_type(8)));

struct __align__(8) Edge { int s; float w; };

// fp32 -> bf16 hi/lo split (RNE both times); hi+lo carries ~16 mantissa bits
__device__ inline void split2(float f, short& h, short& l) {
    unsigned u  = __builtin_bit_cast(unsigned, f);
    unsigned hr = (u + 0x7fffu + ((u >> 16) & 1u)) >> 16;
    h = (short)hr;
    float hf = __builtin_bit_cast(float, hr << 16);
    float r  = f - hf;
    unsigned u2 = __builtin_bit_cast(unsigned, r);
    unsigned lr = (u2 + 0x7fffu + ((u2 >> 16) & 1u)) >> 16;
    l = (short)lr;
}
__device__ inline f32x4 mfma_bf16(s16x8 a, s16x8 b, f32x4 c) {
    return __builtin_amdgcn_mfma_f32_16x16x32_bf16(
        __builtin_bit_cast(bf16x8, a), __builtin_bit_cast(bf16x8, b), c, 0, 0, 0);
}

// ---------------- small utility kernels ----------------
__global__ __launch_bounds__(256) void k_zero_int(int* p, int n) {
    int i = blockIdx.x * 256 + threadIdx.x;
    if (i < n) p[i] = 0;
}

// ---------------- CSR build: 1 atomic/edge, 4-way sharded counters ----------------
__global__ __launch_bounds__(256) void k_hist_rank(const int* __restrict__ dst,
                                                   int* __restrict__ cnt4,
                                                   int* __restrict__ rank) {
    int e = blockIdx.x * 256 + threadIdx.x;
    if (e < EE) {
        int s = e & 3;
        rank[e] = atomicAdd(&cnt4[s * NPAD + dst[e]], 1);
    }
}
// block-local exclusive scan over per-node TOTALS (sum of 4 shards)
__global__ __launch_bounds__(256) void k_scan1(const int* __restrict__ cnt4,
                                               int* __restrict__ excl,
                                               int* __restrict__ blksum) {
    __shared__ int sh[256];
    int tid = threadIdx.x;
    int i = blockIdx.x * 256 + tid;
    int v = 0;
    if (i < NN)
        v = cnt4[i] + cnt4[NPAD + i] + cnt4[2 * NPAD + i] + cnt4[3 * NPAD + i];
    sh[tid] = v;
    __syncthreads();
    #pragma unroll
    for (int off = 1; off < 256; off <<= 1) {
        int x = (tid >= off) ? sh[tid - off] : 0;
        __syncthreads();
        sh[tid] += x;
        __syncthreads();
    }
    if (i < NN) excl[i] = sh[tid] - v;
    if (tid == 255) blksum[blockIdx.x] = sh[255];
}
// per-node prefix across shards, in place: cnt4[s][i] -> sum_{s'<s} cnt4[s'][i]
__global__ __launch_bounds__(256) void k_shardoff(int* __restrict__ cnt4) {
    int i = blockIdx.x * 256 + threadIdx.x;
    if (i >= NN) return;
    int c0 = cnt4[i], c1 = cnt4[NPAD + i], c2 = cnt4[2 * NPAD + i];
    cnt4[i] = 0;
    cnt4[NPAD + i] = c0;
    cnt4[2 * NPAD + i] = c0 + c1;
    cnt4[3 * NPAD + i] = c0 + c1 + c2;
}
__global__ __launch_bounds__(256) void k_scan2(int* blksum, int nblk) {
    __shared__ int sh[256];
    int tid = threadIdx.x;
    sh[tid] = (tid < nblk) ? blksum[tid] : 0;
    __syncthreads();
    #pragma unroll
    for (int off = 1; off < 256; off <<= 1) {
        int x = (tid >= off) ? sh[tid - off] : 0;
        __syncthreads();
        sh[tid] += x;
        __syncthreads();
    }
    if (tid < nblk) blksum[tid] = sh[tid];
}
__global__ __launch_bounds__(256) void k_scan3(const int* __restrict__ excl,
                                               const int* __restrict__ blksum,
                                               int* __restrict__ rowptr) {
    int i = blockIdx.x * 256 + threadIdx.x;
    if (i < NN)
        rowptr[i] = excl[i] + (blockIdx.x > 0 ? blksum[blockIdx.x - 1] : 0);
    if (i == 0) rowptr[NN] = EE;
}
__global__ __launch_bounds__(256) void k_place2(const int* __restrict__ src,
                                                const int* __restrict__ dst,
                                                const float* __restrict__ w,
                                                const int* __restrict__ rowptr,
                                                const int* __restrict__ shardoff,
                                                const int* __restrict__ rank,
                                                Edge* __restrict__ csr_e) {
    int e = blockIdx.x * 256 + threadIdx.x;
    if (e >= EE) return;
    int d = dst[e];
    int s = e & 3;
    int slot = rowptr[d] + shardoff[s * NPAD + d] + rank[e];
    Edge ed; ed.s = src[e]; ed.w = w[e];
    csr_e[slot] = ed;
}
__global__ __launch_bounds__(256) void k_deg_dinv(const int* __restrict__ rowptr,
                                                  const Edge* __restrict__ csr_e,
                                                  float* __restrict__ dinv) {
    int i = blockIdx.x * 256 + threadIdx.x;
    if (i >= NN) return;
    int e0 = rowptr[i], e1 = rowptr[i + 1];
    float s = 1.0f;
    for (int e = e0; e < e1; e++) s += csr_e[e].w;
    dinv[i] = rsqrtf(s);
}
// fold dinv[src] into edge weight: ed.w = w * dinv[s]
__global__ __launch_bounds__(256) void k_edge_coef(Edge* __restrict__ csr_e,
                                                   const float* __restrict__ dinv) {
    int e = blockIdx.x * 256 + threadIdx.x;
    if (e < EE) {
        Edge ed = csr_e[e];
        ed.w *= dinv[ed.s];
        csr_e[e] = ed;
    }
}

// ---------------- all weights: transpose + bf16 hi/lo split (one kernel) ----------------
__device__ inline void cvt_one(const float* W, short* Th, short* Tl, int idx, int K) {
    int k = idx >> 7, c = idx & 127;
    short h, l;
    split2(W[idx], h, l);
    Th[c * K + k] = h;
    Tl[c * K + k] = l;
}
__global__ __launch_bounds__(256) void k_cvt_all(const float* __restrict__ W1,
                                                 const float* __restrict__ W2,
                                                 const float* __restrict__ Wf1,
                                                 short* W1th, short* W1tl,
                                                 short* W2th, short* W2tl,
                                                 short* Wfth, short* Wftl) {
    int idx = blockIdx.x * 256 + threadIdx.x;
    if (idx < 16384)       cvt_one(W1,  W1th, W1tl, idx, 128);
    else if (idx < 32768)  cvt_one(W2,  W2th, W2tl, idx - 16384, 128);
    else if (idx < 81920)  cvt_one(Wf1, Wfth, Wftl, idx - 32768, 384);
}

// ---------------- MFMA split-bf16 GEMM with optional BN fold, fp16 output ----------------
__global__ __launch_bounds__(256) void gemm_mfma(const float* __restrict__ X,
                                                 const float* __restrict__ sc,
                                                 const float* __restrict__ sh,
                                                 const short* __restrict__ WTh,
                                                 const short* __restrict__ WTl,
                                                 __half* __restrict__ Y, int n) {
    __shared__ __align__(16) short As[2][64][40];
    __shared__ __align__(16) short Bs[2][128][40];
    int tid  = threadIdx.x;
    int row0 = blockIdx.x * 64;
    int w = tid >> 6, lane = tid & 63;
    int wr = w >> 1, wc = w & 1;
    int fr = lane & 15, fq = lane >> 4;
    f32x4 acc[2][4] = {};
    for (int k0 = 0; k0 < 128; k0 += 32) {
        {
            int r = tid >> 2, seg = tid & 3;
            int gr = row0 + r;
            float f[8];
            if (gr < n) {
                float4 v0 = *(const float4*)&X[(size_t)gr * 128 + k0 + seg * 8];
                float4 v1 = *(const float4*)&X[(size_t)gr * 128 + k0 + seg * 8 + 4];
                f[0]=v0.x; f[1]=v0.y; f[2]=v0.z; f[3]=v0.w;
                f[4]=v1.x; f[5]=v1.y; f[6]=v1.z; f[7]=v1.w;
            } else {
                #pragma unroll
                for (int i = 0; i < 8; i++) f[i] = 0.f;
            }
            if (sc) {
                float scv[8], shv[8];
                *(float4*)&scv[0] = *(const float4*)&sc[k0 + seg * 8];
                *(float4*)&scv[4] = *(const float4*)&sc[k0 + seg * 8 + 4];
                *(float4*)&shv[0] = *(const float4*)&sh[k0 + seg * 8];
                *(float4*)&shv[4] = *(const float4*)&sh[k0 + seg * 8 + 4];
                #pragma unroll
                for (int i = 0; i < 8; i++) f[i] = fmaf(f[i], scv[i], shv[i]);
            }
            short h[8], l[8];
            #pragma unroll
            for (int i = 0; i < 8; i++) split2(f[i], h[i], l[i]);
            *(s16x8*)&As[0][r][seg * 8] = *(s16x8*)h;
            *(s16x8*)&As[1][r][seg * 8] = *(s16x8*)l;
        }
        #pragma unroll
        for (int rd = 0; rd < 2; rd++) {
            int idx = rd * 256 + tid;
            int c = idx >> 2, seg = idx & 3;
            *(s16x8*)&Bs[0][c][seg * 8] = *(const s16x8*)&WTh[c * 128 + k0 + seg * 8];
            *(s16x8*)&Bs[1][c][seg * 8] = *(const s16x8*)&WTl[c * 128 + k0 + seg * 8];
        }
        __syncthreads();
        s16x8 ah[2], al[2], bh[4], bl[4];
        #pragma unroll
        for (int m = 0; m < 2; m++) {
            int r = wr * 32 + m * 16 + fr;
            ah[m] = *(s16x8*)&As[0][r][fq * 8];
            al[m] = *(s16x8*)&As[1][r][fq * 8];
        }
        #pragma unroll
        for (int nf = 0; nf < 4; nf++) {
            int c = wc * 64 + nf * 16 + fr;
            bh[nf] = *(s16x8*)&Bs[0][c][fq * 8];
            bl[nf] = *(s16x8*)&Bs[1][c][fq * 8];
        }
        #pragma unroll
        for (int m = 0; m < 2; m++)
            #pragma unroll
            for (int nf = 0; nf < 4; nf++) {
                acc[m][nf] = mfma_bf16(ah[m], bh[nf], acc[m][nf]);
                acc[m][nf] = mfma_bf16(ah[m], bl[nf], acc[m][nf]);
                acc[m][nf] = mfma_bf16(al[m], bh[nf], acc[m][nf]);
            }
        __syncthreads();
    }
    #pragma unroll
    for (int m = 0; m < 2; m++)
        #pragma unroll
        for (int nf = 0; nf < 4; nf++)
            #pragma unroll
            for (int j = 0; j < 4; j++) {
                int gr = row0 + wr * 32 + m * 16 + fq * 4 + j;
                int gc = wc * 64 + nf * 16 + fr;
                if (gr < n) Y[(size_t)gr * 128 + gc] = __float2half(acc[m][nf][j]);
            }
}

// ---------------- MFMA head with BN fold on X1/X2 segments ----------------
__global__ __launch_bounds__(256) void gemm_head_mfma(const float* __restrict__ X0,
                                                      const float* __restrict__ X1,
                                                      const float* __restrict__ X2,
                                                      const float* __restrict__ sc1,
                                                      const float* __restrict__ sh1,
                                                      const float* __restrict__ sc2,
                                                      const float* __restrict__ sh2,
                                                      const short* __restrict__ WTh,
                                                      const short* __restrict__ WTl,
                                                      const float* __restrict__ bf1,
                                                      const float* __restrict__ Wf2,
                                                      const float* __restrict__ bf2,
                                                      float* __restrict__ out) {
    __shared__ __align__(16) short As[2][64][40];
    __shared__ __align__(16) short Bs[2][128][40];
    __shared__ float red[64];
    int tid  = threadIdx.x;
    int row0 = blockIdx.x * 64;
    int w = tid >> 6, lane = tid & 63;
    int wr = w >> 1, wc = w & 1;
    int fr = lane & 15, fq = lane >> 4;
    f32x4 acc[2][4] = {};
    for (int k0 = 0; k0 < 384; k0 += 32) {
        const float* S   = (k0 < 128) ? X0 : (k0 < 256) ? X1 : X2;
        const float* scp = (k0 < 128) ? nullptr : (k0 < 256) ? sc1 : sc2;
        const float* shp = (k0 < 128) ? nullptr : (k0 < 256) ? sh1 : sh2;
        int kb = k0 & 127;
        {
            int r = tid >> 2, seg = tid & 3;
            int gr = row0 + r;
            float f[8];
            if (gr < NN) {
                float4 v0 = *(const float4*)&S[(size_t)gr * 128 + kb + seg * 8];
                float4 v1 = *(const float4*)&S[(size_t)gr * 128 + kb + seg * 8 + 4];
                f[0]=v0.x; f[1]=v0.y; f[2]=v0.z; f[3]=v0.w;
                f[4]=v1.x; f[5]=v1.y; f[6]=v1.z; f[7]=v1.w;
            } else {
                #pragma unroll
                for (int i = 0; i < 8; i++) f[i] = 0.f;
            }
            if (scp) {
                float scv[8], shv[8];
                *(float4*)&scv[0] = *(const float4*)&scp[kb + seg * 8];
                *(float4*)&scv[4] = *(const float4*)&scp[kb + seg * 8 + 4];
                *(float4*)&shv[0] = *(const float4*)&shp[kb + seg * 8];
                *(float4*)&shv[4] = *(const float4*)&shp[kb + seg * 8 + 4];
                #pragma unroll
                for (int i = 0; i < 8; i++) f[i] = fmaf(f[i], scv[i], shv[i]);
            }
            short h[8], l[8];
            #pragma unroll
            for (int i = 0; i < 8; i++) split2(f[i], h[i], l[i]);
            *(s16x8*)&As[0][r][seg * 8] = *(s16x8*)h;
            *(s16x8*)&As[1][r][seg * 8] = *(s16x8*)l;
        }
        #pragma unroll
        for (int rd = 0; rd < 2; rd++) {
            int idx = rd * 256 + tid;
            int c = idx >> 2, seg = idx & 3;
            *(s16x8*)&Bs[0][c][seg * 8] = *(const s16x8*)&WTh[c * 384 + k0 + seg * 8];
            *(s16x8*)&Bs[1][c][seg * 8] = *(const s16x8*)&WTl[c * 384 + k0 + seg * 8];
        }
        __syncthreads();
        s16x8 ah[2], al[2], bh[4], bl[4];
        #pragma unroll
        for (int m = 0; m < 2; m++) {
            int r = wr * 32 + m * 16 + fr;
            ah[m] = *(s16x8*)&As[0][r][fq * 8];
            al[m] = *(s16x8*)&As[1][r][fq * 8];
        }
        #pragma unroll
        for (int nf = 0; nf < 4; nf++) {
            int c = wc * 64 + nf * 16 + fr;
            bh[nf] = *(s16x8*)&Bs[0][c][fq * 8];
            bl[nf] = *(s16x8*)&Bs[1][c][fq * 8];
        }
        #pragma unroll
        for (int m = 0; m < 2; m++)
            #pragma unroll
            for (int nf = 0; nf < 4; nf++) {
                acc[m][nf] = mfma_bf16(ah[m], bh[nf], acc[m][nf]);
                acc[m][nf] = mfma_bf16(ah[m], bl[nf], acc[m][nf]);
                acc[m][nf] = mfma_bf16(al[m], bh[nf], acc[m][nf]);
            }
        __syncthreads();
    }
    if (tid < 64) red[tid] = 0.f;
    __syncthreads();
    float ps[2][4] = {};
    #pragma unroll
    for (int m = 0; m < 2; m++)
        #pragma unroll
        for (int nf = 0; nf < 4; nf++) {
            int gc = wc * 64 + nf * 16 + fr;
            float b1v = bf1[gc];
            float w2v = Wf2[gc];
            #pragma unroll
            for (int j = 0; j < 4; j++) {
                float u = fmaxf(acc[m][nf][j] + b1v, 0.f);
                ps[m][j] = fmaf(u, w2v, ps[m][j]);
            }
        }
    #pragma unroll
    for (int off = 1; off <= 8; off <<= 1)
        #pragma unroll
        for (int m = 0; m < 2; m++)
            #pragma unroll
            for (int j = 0; j < 4; j++)
                ps[m][j] += __shfl_xor(ps[m][j], off, 64);
    if (fr == 0) {
        #pragma unroll
        for (int m = 0; m < 2; m++)
            #pragma unroll
            for (int j = 0; j < 4; j++)
                atomicAdd(&red[wr * 32 + m * 16 + fq * 4 + j], ps[m][j]);
    }
    __syncthreads();
    if (tid < 64 && row0 + tid < NN)
        out[row0 + tid] = fmaxf(red[tid] + bf2[0], 0.f);
}

// ---------------- aggregate: 256 thr, 4 waves x 8 nodes; 4 edges x 16 lanes x 16B ----------------
// (round-7 proven config) h[d] = relu( (t[d]*dinv_d + sum_e coef_e*t[s_e]) * dinv_d + b )
__global__ __launch_bounds__(256) void k_agg_stats(const __half* __restrict__ t,
                                                   const float* __restrict__ dinv,
                                                   const float* __restrict__ b,
                                                   const int* __restrict__ rowptr,
                                                   const Edge* __restrict__ csr_e,
                                                   float* __restrict__ h,
                                                   float* __restrict__ partS,
                                                   float* __restrict__ partSS) {
    int wv   = threadIdx.x >> 6;
    int lane = threadIdx.x & 63;
    int sub  = lane >> 4;        // edge slot 0..3
    int sl   = lane & 15;        // col group: 8 cols each
    float bb[8];
    *(float4*)&bb[0] = *(const float4*)&b[sl * 8];
    *(float4*)&bb[4] = *(const float4*)&b[sl * 8 + 4];
    float sS[8] = {}, sSS[8] = {};
    #pragma unroll 1
    for (int ni = 0; ni < 8; ni++) {
        int wid = blockIdx.x * 32 + wv * 8 + ni;
        if (wid >= NN) break;
        float di = dinv[wid];
        float acc[8];
        if (sub == 0) {              // self-loop term
            s16x8 raw = *(const s16x8*)&t[(size_t)wid * 128 + sl * 8];
            union { s16x8 r; __half2 h2[4]; } u; u.r = raw;
            #pragma unroll
            for (int i = 0; i < 4; i++) {
                float2 f = __half22float2(u.h2[i]);
                acc[2 * i]     = f.x * di;
                acc[2 * i + 1] = f.y * di;
            }
        } else {
            #pragma unroll
            for (int i = 0; i < 8; i++) acc[i] = 0.f;
        }
        int e0 = rowptr[wid], e1 = rowptr[wid + 1];
        #pragma unroll 2
        for (int e = e0; e < e1; e += 4) {
            int ee   = e + sub;
            bool v   = ee < e1;
            Edge ed  = csr_e[v ? ee : e0];                  // 8B load (e0 valid: loop ran)
            float cw = v ? ed.w : 0.f;
            s16x8 raw = *(const s16x8*)&t[(size_t)ed.s * 128 + sl * 8];  // 16B gather
            union { s16x8 r; __half2 h2[4]; } u; u.r = raw;
            #pragma unroll
            for (int i = 0; i < 4; i++) {
                float2 f = __half22float2(u.h2[i]);
                acc[2 * i]     = fmaf(f.x, cw, acc[2 * i]);
                acc[2 * i + 1] = fmaf(f.y, cw, acc[2 * i + 1]);
            }
        }
        // reduce 4 edge slots
        #pragma unroll
        for (int i = 0; i < 8; i++) {
            acc[i] += __shfl_xor(acc[i], 16, 64);
            acc[i] += __shfl_xor(acc[i], 32, 64);
        }
        if (sub == 0) {
            float hv[8];
            #pragma unroll
            for (int i = 0; i < 8; i++) {
                hv[i] = fmaxf(fmaf(acc[i], di, bb[i]), 0.f);
                sS[i]  += hv[i];
                sSS[i] += hv[i] * hv[i];
            }
            *(float4*)&h[(size_t)wid * 128 + sl * 8]     = *(float4*)&hv[0];
            *(float4*)&h[(size_t)wid * 128 + sl * 8 + 4] = *(float4*)&hv[4];
        }
    }
    __shared__ float s_s[4][128], s_ss[4][128];
    if (sub == 0) {
        #pragma unroll
        for (int i = 0; i < 8; i++) {
            s_s [wv][sl * 8 + i] = sS[i];
            s_ss[wv][sl * 8 + i] = sSS[i];
        }
    }
    __syncthreads();
    if (threadIdx.x < 128) {
        int c = threadIdx.x;
        float S  = s_s [0][c] + s_s [1][c] + s_s [2][c] + s_s [3][c];
        float SS = s_ss[0][c] + s_ss[1][c] + s_ss[2][c] + s_ss[3][c];
        partS [blockIdx.x * 128 + c] = S;
        partSS[blockIdx.x * 128 + c] = SS;
    }
}

// ---------------- parallel reduce partials -> BN scale/shift ----------------
__global__ __launch_bounds__(256) void k_stats(const float* __restrict__ partS,
                                               const float* __restrict__ partSS,
                                               int nblk,
                                               const float* __restrict__ g,
                                               const float* __restrict__ be,
                                               float* __restrict__ scale,
                                               float* __restrict__ shift) {
    int c   = blockIdx.x;
    int tid = threadIdx.x;
    float s = 0.f, ss = 0.f;
    for (int b = tid; b < nblk; b += 256) {
        s  += partS [b * 128 + c];
        ss += partSS[b * 128 + c];
    }
    #pragma unroll
    for (int off = 32; off > 0; off >>= 1) {
        s  += __shfl_down(s,  off, 64);
        ss += __shfl_down(ss, off, 64);
    }
    __shared__ float sh_s[4], sh_ss[4];
    int wv = tid >> 6, lane = tid & 63;
    if (lane == 0) { sh_s[wv] = s; sh_ss[wv] = ss; }
    __syncthreads();
    if (tid == 0) {
        float S  = sh_s[0]  + sh_s[1]  + sh_s[2]  + sh_s[3];
        float SS = sh_ss[0] + sh_ss[1] + sh_ss[2] + sh_ss[3];
        float mean = S / (float)NN;
        float var  = SS / (float)NN - mean * mean;
        float sc   = g[c] * rsqrtf(var + BN_EPS);
        scale[c] = sc;
        shift[c] = be[c] - mean * sc;
    }
}

// ---------------- launch ----------------
extern "C" void kernel_launch(void* const* d_in, const int* in_sizes, int n_in,
                              void* d_out, int out_size, void* d_ws, size_t ws_size,
                              hipStream_t stream) {
    const float* x   = (const float*)d_in[0];
    const int*   ei  = (const int*)d_in[1];
    const float* ew  = (const float*)d_in[2];
    const float* W1  = (const float*)d_in[3];
    const float* b1  = (const float*)d_in[4];
    const float* W2  = (const float*)d_in[5];
    const float* b2  = (const float*)d_in[6];
    const float* g1  = (const float*)d_in[7];
    const float* be1 = (const float*)d_in[8];
    const float* g2  = (const float*)d_in[9];
    const float* be2 = (const float*)d_in[10];
    const float* Wf1 = (const float*)d_in[11];
    const float* bf1 = (const float*)d_in[12];
    const float* Wf2 = (const float*)d_in[13];
    const float* bf2 = (const float*)d_in[14];
    float* out = (float*)d_out;

    const int* src = ei;
    const int* dst = ei + EE;

    const int NAGG = (NN + 31) / 32;  // 1563 blocks (32 nodes each, 4 waves x 8)

    // workspace carve
    float* w = (float*)d_ws;
    __half* t      = (__half*)w;  w += (size_t)NN * 64;    // NN*128 halves
    float* h1      = w;  w += (size_t)NN * 128;
    float* h2      = w;  w += (size_t)NN * 128;
    float* dinv    = w;  w += NPAD;
    float* partS   = w;  w += (size_t)NAGG * 128;
    float* partSS  = w;  w += (size_t)NAGG * 128;
    float* scale1  = w;  w += 128;
    float* shift1  = w;  w += 128;
    float* scale2  = w;  w += 128;
    float* shift2  = w;  w += 128;
    Edge* csr_e    = (Edge*)w;  w += 2 * (size_t)EE;       // 8B per edge
    int* iw        = (int*)w;
    int* rowptr    = iw; iw += 50056;
    int* cnt4      = iw; iw += 4 * NPAD;                   // sharded counters / shard offsets
    int* excl      = iw; iw += NPAD;
    int* blksum    = iw; iw += 256;
    short* sw      = (short*)iw;
    short* W1th = sw; sw += 128 * 128;
    short* W1tl = sw; sw += 128 * 128;
    short* W2th = sw; sw += 128 * 128;
    short* W2tl = sw; sw += 128 * 128;
    short* Wfth = sw; sw += 128 * 384;
    short* Wftl = sw; sw += 128 * 384;
    // rank aliases t region: CSR build completes before gemm writes t (same stream)
    int* rank = (int*)t;

    const int GN = (NN + 255) / 256;
    const int GE = (EE + 255) / 256;
    const int NBLK = (NN + 63) / 64;  // 782

    // weights (one kernel) + CSR build (sharded hist)
    k_cvt_all<<<(81920 + 255) / 256, 256, 0, stream>>>(W1, W2, Wf1, W1th, W1tl,
                                                       W2th, W2tl, Wfth, Wftl);
    k_zero_int<<<(4 * NPAD + 255) / 256, 256, 0, stream>>>(cnt4, 4 * NPAD);
    k_hist_rank<<<GE, 256, 0, stream>>>(dst, cnt4, rank);
    k_scan1<<<GN, 256, 0, stream>>>(cnt4, excl, blksum);
    k_shardoff<<<GN, 256, 0, stream>>>(cnt4);
    k_scan2<<<1, 256, 0, stream>>>(blksum, GN);
    k_scan3<<<GN, 256, 0, stream>>>(excl, blksum, rowptr);
    k_place2<<<GE, 256, 0, stream>>>(src, dst, ew, rowptr, cnt4, rank, csr_e);
    k_deg_dinv<<<GN, 256, 0, stream>>>(rowptr, csr_e, dinv);
    k_edge_coef<<<GE, 256, 0, stream>>>(csr_e, dinv);

    // layer 1
    gemm_mfma<<<NBLK, 256, 0, stream>>>(x, nullptr, nullptr, W1th, W1tl, t, NN);
    k_agg_stats<<<NAGG, 256, 0, stream>>>(t, dinv, b1, rowptr, csr_e, h1, partS, partSS);
    k_stats<<<128, 256, 0, stream>>>(partS, partSS, NAGG, g1, be1, scale1, shift1);

    // layer 2 (BN1 folded into staging)
    gemm_mfma<<<NBLK, 256, 0, stream>>>(h1, scale1, shift1, W2th, W2tl, t, NN);
    k_agg_stats<<<NAGG, 256, 0, stream>>>(t, dinv, b2, rowptr, csr_e, h2, partS, partSS);
    k_stats<<<128, 256, 0, stream>>>(partS, partSS, NAGG, g2, be2, scale2, shift2);

    // head (BN1/BN2 folded into staging of X1/X2)
    gemm_head_mfma<<<NBLK, 256, 0, stream>>>(x, h1, h2, scale1, shift1, scale2, shift2,
                                             Wfth, Wftl, bf1, Wf2, bf2, out);
}